// Round 5
// baseline (881.999 us; speedup 1.0000x reference)
//
#include <hip/hip_runtime.h>
#include <hip/hip_cooperative_groups.h>

namespace cg = cooperative_groups;

// ---------------------------------------------------------------------------
// GGNN message passing, MI355X/gfx950.  Round 14:
//   - agg_gru v4: SAME verified math as R13, quarter-size blocks.
//     R13 post-mortem: traffic fix confirmed (327->66MB) but 92us with all
//     pipes <11% and occ 29% => latency-bound with ~1.2 blocks/CU.  v4:
//     32-node tile, 256 threads, 26KB LDS -> 5-6 independent blocks/CU.
//     Phase A: dbuf parity staging (R13), wave owns 32 cols, acc[2][2].
//     Phase B: two gate-half passes, acc[4][2], VGPR<=~90 @ (256,5).
//   - build_kernel: prep + hist + scan + scan_top + finalize + fill +
//     gather_s fused into ONE cooperative launch (768x256, co-residency
//     guaranteed at 4 blocks/CU capacity); 6 grid.sync()s replace 6
//     launch boundaries (hidden tier was 181us over 7 dependent launches).
// Lessons: no gather-into-GEMM fusion (R6); no K-merging (R7); LDS-staged
// coalesced out stores (R5); (dst,type) CSR (R6/R9); no per-lane weight
// streaming / watch WRITE_SIZE for spill (R12).
// ---------------------------------------------------------------------------

typedef __attribute__((ext_vector_type(8))) short short8;
typedef __attribute__((ext_vector_type(4))) float floatx4;

#define HID 128
#define NTY 4

__device__ __forceinline__ unsigned short f2bf(float f) {
    unsigned int u = __float_as_uint(f);
    unsigned int r = (u + 0x7fffu + ((u >> 16) & 1u)) >> 16;  // RNE
    return (unsigned short)r;
}
__device__ __forceinline__ float bf2f(unsigned int lo16) {
    return __uint_as_float(lo16 << 16);
}
__device__ __forceinline__ float frcp(float x) { return __builtin_amdgcn_rcpf(x); }

// ---- build_kernel: all pre-GEMM work in one cooperative launch ------------
// P0 prep(cvt_h|Wc|Wg|bias4|zero deg4) -> P1 hist -> P2 block scans ->
// P3 top scan -> P4 finalize -> P5 fill -> P6 gather_s v4.

struct BuildArgs {
    const float* h; unsigned short* hbf;
    const float* W; unsigned short* Wc;
    const float* wih; const float* whh; unsigned short* Wg;
    float* bias4; const float* bih; const float* bhh;
    int* deg4; int* rowptr4; int* cursor4; int* blocksum; int* blockoff; int* csr;
    const int* src; const int* dst; const int* ety;
    float4* cnt4; unsigned int* Su;
    int M, E, N4, total4;
};

__global__ __launch_bounds__(256, 4) void build_kernel(BuildArgs a) {
    cg::grid_group grid = cg::this_grid();
    __shared__ int s[256];
    const int t = threadIdx.x;
    const int gtid = blockIdx.x * 256 + t;
    const int nth = gridDim.x * 256;

    // ---- P0: prep + zero deg4 ----
    for (int i = gtid; i < a.total4; i += nth) {
        float4 v = ((const float4*)a.h)[i];
        uint2 o;
        o.x = (unsigned int)f2bf(v.x) | ((unsigned int)f2bf(v.y) << 16);
        o.y = (unsigned int)f2bf(v.z) | ((unsigned int)f2bf(v.w) << 16);
        ((uint2*)a.hbf)[i] = o;
    }
    for (int idx = gtid; idx < 128 * 512; idx += nth) {
        int j = idx >> 9, rem = idx & 511;
        int ty = rem >> 7, k = rem & 127;
        a.Wc[idx] = f2bf(a.W[(ty * HID + j) * HID + k]);
    }
    for (int idx = gtid; idx < 512 * 256; idx += nth) {
        int row = idx >> 8, k = idx & 255;
        int j = row >> 2, g = row & 3;
        float v = 0.0f;
        if (g == 0)      v = (k < 128) ? a.wih[j * 128 + k]         : a.whh[j * 128 + (k - 128)];
        else if (g == 1) v = (k < 128) ? a.wih[(128 + j) * 128 + k] : a.whh[(128 + j) * 128 + (k - 128)];
        else if (g == 2) v = (k < 128) ? a.wih[(256 + j) * 128 + k] : 0.0f;
        else             v = (k < 128) ? 0.0f : a.whh[(256 + j) * 128 + (k - 128)];
        a.Wg[idx] = f2bf(v);
    }
    if (gtid < 128) {
        float4 v;
        v.x = a.bih[gtid] + a.bhh[gtid];
        v.y = a.bih[128 + gtid] + a.bhh[128 + gtid];
        v.z = a.bih[256 + gtid];
        v.w = a.bhh[256 + gtid];
        ((float4*)a.bias4)[gtid] = v;
    }
    for (int i = gtid; i < a.N4; i += nth) a.deg4[i] = 0;
    grid.sync();

    // ---- P1: histogram ----
    for (int e = gtid; e < a.E; e += nth)
        atomicAdd(&a.deg4[a.dst[e] * 4 + a.ety[e]], 1);
    grid.sync();

    // ---- P2: per-1024-chunk exclusive scans ----
    const int nbscan = (a.N4 + 1023) >> 10;
    for (int vb = blockIdx.x; vb < nbscan; vb += gridDim.x) {
        int base = vb * 1024 + t * 4;
        int v0 = 0, v1 = 0, v2 = 0, v3 = 0;
        if (base + 3 < a.N4) {
            v0 = a.deg4[base]; v1 = a.deg4[base + 1]; v2 = a.deg4[base + 2]; v3 = a.deg4[base + 3];
        } else {
            if (base < a.N4) v0 = a.deg4[base];
            if (base + 1 < a.N4) v1 = a.deg4[base + 1];
            if (base + 2 < a.N4) v2 = a.deg4[base + 2];
        }
        int sum = v0 + v1 + v2 + v3;
        s[t] = sum;
        __syncthreads();
#pragma unroll
        for (int off = 1; off < 256; off <<= 1) {
            int x = (t >= off) ? s[t - off] : 0;
            __syncthreads();
            s[t] += x;
            __syncthreads();
        }
        int ex = s[t] - sum;
        if (base < a.N4) a.rowptr4[base] = ex;
        if (base + 1 < a.N4) a.rowptr4[base + 1] = ex + v0;
        if (base + 2 < a.N4) a.rowptr4[base + 2] = ex + v0 + v1;
        if (base + 3 < a.N4) a.rowptr4[base + 3] = ex + v0 + v1 + v2;
        if (t == 255) a.blocksum[vb] = s[255];
        __syncthreads();
    }
    grid.sync();

    // ---- P3: top-level scan (block 0) ----
    if (blockIdx.x == 0) {
        int v = (t < nbscan) ? a.blocksum[t] : 0;
        s[t] = v;
        __syncthreads();
#pragma unroll
        for (int off = 1; off < 256; off <<= 1) {
            int x = (t >= off) ? s[t - off] : 0;
            __syncthreads();
            s[t] += x;
            __syncthreads();
        }
        if (t < nbscan) a.blockoff[t] = s[t] - v;
    }
    grid.sync();

    // ---- P4: finalize rowptr + cursor + sentinel ----
    for (int i = gtid; i < a.N4; i += nth) {
        int r = a.rowptr4[i] + a.blockoff[i >> 10];
        a.rowptr4[i] = r;
        a.cursor4[i] = r;
    }
    if (gtid == 0) a.rowptr4[a.N4] = a.E;
    grid.sync();

    // ---- P5: fill CSR ----
    for (int e = gtid; e < a.E; e += nth) {
        int pos = atomicAdd(&a.cursor4[a.dst[e] * 4 + a.ety[e]], 1);
        a.csr[pos] = a.src[e];
    }
    grid.sync();

    // ---- P6: gather_s v4 (wave per node, grid-stride) ----
    const int lane = t & 63;
    const int gw = gtid >> 6, nwav = nth >> 6;
    for (int nd = gw; nd < a.M; nd += nwav) {
        int b0 = __builtin_amdgcn_readfirstlane(a.rowptr4[nd * 4]);
        int b1 = __builtin_amdgcn_readfirstlane(a.rowptr4[nd * 4 + 1]);
        int b2 = __builtin_amdgcn_readfirstlane(a.rowptr4[nd * 4 + 2]);
        int b3 = __builtin_amdgcn_readfirstlane(a.rowptr4[nd * 4 + 3]);
        int b4 = __builtin_amdgcn_readfirstlane(a.rowptr4[nd * 4 + 4]);

        float s0 = 0.f, s1 = 0.f;
        float sn0[3], sn1[3];
        const unsigned int* hbu = a.Su ? (const unsigned int*)a.hbf : (const unsigned int*)a.hbf;

        int e = b0;
        while (e + 8 <= b4) {
            int p[8];
            unsigned int u[8];
#pragma unroll
            for (int i = 0; i < 8; ++i) p[i] = a.csr[e + i];
#pragma unroll
            for (int i = 0; i < 8; ++i) u[i] = hbu[(size_t)p[i] * 64 + lane];
#pragma unroll
            for (int i = 0; i < 8; ++i) {
                int idx = e + i;
                if (idx == b1) { sn0[0] = s0; sn1[0] = s1; }
                if (idx == b2) { sn0[1] = s0; sn1[1] = s1; }
                if (idx == b3) { sn0[2] = s0; sn1[2] = s1; }
                s0 += bf2f(u[i] & 0xffffu);
                s1 += bf2f(u[i] >> 16);
            }
            e += 8;
        }
        {
            int rem = b4 - e;
            int p[7];
            unsigned int u[7];
#pragma unroll
            for (int i = 0; i < 7; ++i) if (i < rem) p[i] = a.csr[e + i];
#pragma unroll
            for (int i = 0; i < 7; ++i) if (i < rem) u[i] = hbu[(size_t)p[i] * 64 + lane];
#pragma unroll
            for (int i = 0; i < 7; ++i) {
                if (i < rem) {
                    int idx = e + i;
                    if (idx == b1) { sn0[0] = s0; sn1[0] = s1; }
                    if (idx == b2) { sn0[1] = s0; sn1[1] = s1; }
                    if (idx == b3) { sn0[2] = s0; sn1[2] = s1; }
                    s0 += bf2f(u[i] & 0xffffu);
                    s1 += bf2f(u[i] >> 16);
                }
            }
        }
        if (b1 == b4) { sn0[0] = s0; sn1[0] = s1; }
        if (b2 == b4) { sn0[1] = s0; sn1[1] = s1; }
        if (b3 == b4) { sn0[2] = s0; sn1[2] = s1; }

        size_t base = (size_t)nd * 256 + lane;
        float p0 = 0.f, p1 = 0.f;
#pragma unroll
        for (int ty = 0; ty < 4; ++ty) {
            float c0 = (ty < 3) ? sn0[ty] : s0;
            float c1 = (ty < 3) ? sn1[ty] : s1;
            float a0 = c0 - p0, a1 = c1 - p1;
            p0 = c0; p1 = c1;
            a.Su[base + ty * 64] = (unsigned int)f2bf(a0) | ((unsigned int)f2bf(a1) << 16);
        }
        if (lane == 0)
            a.cnt4[nd] = make_float4((float)(b1 - b0), (float)(b2 - b1),
                                     (float)(b3 - b2), (float)(b4 - b3));
    }
}

// ---- agg_gru v4: fused GEMM->GRU, 32-node tile, 256 threads (4 waves) -----
// Phase A: wave w owns agg cols [w*32,+32); K=512 in 4 BK=128 steps,
//   dbuf parity staging (one barrier/step, R13 scheme).  acc[2][2].
// Handoff: agg(+cnt.eb) -> Xagg[32][136] bf16 (verified D-mapping); bar.
// Phase B: two gate-half passes h=0,1; wave owns rows [h*256+w*64,+64);
//   acc[4][2]; ss 0-3 agg from LDS, ss 4-7 h direct from hbf; Wg from L2.
// Epilogue per pass: fast sigmoid/tanh, Outs[32][68] f32 overlay, coalesced.

__global__ __launch_bounds__(256, 5) void agg_gru(const unsigned short* __restrict__ S,
                                                  const unsigned short* __restrict__ Wc,
                                                  const unsigned short* __restrict__ Wg,
                                                  const unsigned short* __restrict__ hbf,
                                                  const float4* __restrict__ cnt4,
                                                  const float* __restrict__ eb,
                                                  const float4* __restrict__ bias4,
                                                  float* __restrict__ out, int M) {
    __shared__ __align__(16) unsigned char smem[26112];
    typedef unsigned short row136[136];
    row136* Sb0  = (row136*)smem;                  // [32][136]  8704B
    row136* Sb1  = (row136*)(smem + 8704);         // [32][136]  8704B
    row136* Xagg = (row136*)(smem + 17408);        // [32][136]  8704B
    float (*Outs)[68] = (float (*)[68])smem;       // [32][68] f32 overlay on Sb0

    const int tid = threadIdx.x;
    const int m0 = blockIdx.x * 32;
    const int lane = tid & 63, w = tid >> 6;       // w in 0..3
    const int lm = lane & 15, quad = lane >> 4;

    // staging: thread stages rows {r0, 16+r0} x 8 shorts at col sc
    const int r0 = tid >> 4, sc = (tid & 15) * 8;
    const int gA = m0 + r0, gB = m0 + 16 + r0;
    const bool vA = gA < M, vB = gB < M;
    const unsigned short* SpA = S + (size_t)(vA ? gA : 0) * 512 + sc;
    const unsigned short* SpB = S + (size_t)(vB ? gB : 0) * 512 + sc;
    const uint4 Z = {0u, 0u, 0u, 0u};

    uint4 c0v = vA ? *(const uint4*)SpA : Z;
    uint4 c1v = vB ? *(const uint4*)SpB : Z;

    floatx4 accA[2][2];
#pragma unroll
    for (int x = 0; x < 2; ++x)
#pragma unroll
        for (int y = 0; y < 2; ++y) accA[x][y] = (floatx4){0.f, 0.f, 0.f, 0.f};

#pragma unroll 1
    for (int c = 0; c < 4; ++c) {
        uint4 n0v = Z, n1v = Z;
        if (c < 3) {                               // next-step loads EARLY
            n0v = vA ? *(const uint4*)(SpA + (c + 1) * 128) : Z;
            n1v = vB ? *(const uint4*)(SpB + (c + 1) * 128) : Z;
        }
        row136* buf = (c & 1) ? Sb1 : Sb0;
        *(uint4*)&buf[r0][sc] = c0v;
        *(uint4*)&buf[16 + r0][sc] = c1v;
        __syncthreads();                           // staging visible
#pragma unroll
        for (int ss = 0; ss < 4; ++ss) {
            short8 av0 = *(const short8*)&buf[lm][ss * 32 + quad * 8];
            short8 av1 = *(const short8*)&buf[16 + lm][ss * 32 + quad * 8];
#pragma unroll
            for (int ni = 0; ni < 2; ++ni) {
                short8 bw = *(const short8*)(Wc + (size_t)(w * 32 + ni * 16 + lm) * 512 + c * 128 + ss * 32 + quad * 8);
                accA[0][ni] = __builtin_amdgcn_mfma_f32_16x16x32_bf16(av0, bw, accA[0][ni], 0, 0, 0);
                accA[1][ni] = __builtin_amdgcn_mfma_f32_16x16x32_bf16(av1, bw, accA[1][ni], 0, 0, 0);
            }
        }
        c0v = n0v; c1v = n1v;
        // no trailing barrier: parity dbuf; step c+2's writes are fenced by
        // step c+1's barrier (verified R13 scheme).
    }

    // handoff: agg(+cnt.eb) -> Xagg.  D: row nl=mi*16+quad*4+r, col j.
#pragma unroll
    for (int ni = 0; ni < 2; ++ni) {
        int j = w * 32 + ni * 16 + lm;
        float e0 = eb[j], e1 = eb[HID + j], e2 = eb[2 * HID + j], e3 = eb[3 * HID + j];
#pragma unroll
        for (int mi = 0; mi < 2; ++mi) {
#pragma unroll
            for (int r = 0; r < 4; ++r) {
                int nl = mi * 16 + quad * 4 + r;
                int gn = m0 + nl;
                if (gn >= M) gn = M - 1;
                float4 c4 = cnt4[gn];
                float v = accA[mi][ni][r] + c4.x * e0 + c4.y * e1 + c4.z * e2 + c4.w * e3;
                Xagg[nl][j] = f2bf(v);
            }
        }
    }
    __syncthreads();  // Xagg complete; Sb region dead -> Outs overlay OK

    // ---- phase B: two gate-half passes ----
#pragma unroll 1
    for (int h = 0; h < 2; ++h) {
        floatx4 accB[4][2];
#pragma unroll
        for (int x = 0; x < 4; ++x)
#pragma unroll
            for (int y = 0; y < 2; ++y) accB[x][y] = (floatx4){0.f, 0.f, 0.f, 0.f};

#pragma unroll
        for (int ss = 0; ss < 8; ++ss) {
            short8 bfr[2];
#pragma unroll
            for (int ni = 0; ni < 2; ++ni) {
                if (ss < 4) {
                    bfr[ni] = *(const short8*)&Xagg[ni * 16 + lm][ss * 32 + quad * 8];
                } else {
                    int gr = m0 + ni * 16 + lm;
                    if (gr >= M) gr = M - 1;
                    bfr[ni] = *(const short8*)(hbf + (size_t)gr * HID + (ss - 4) * 32 + quad * 8);
                }
            }
#pragma unroll
            for (int mi = 0; mi < 4; ++mi) {
                short8 af = *(const short8*)(Wg + (size_t)(h * 256 + w * 64 + mi * 16 + lm) * 256 + ss * 32 + quad * 8);
                accB[mi][0] = __builtin_amdgcn_mfma_f32_16x16x32_bf16(af, bfr[0], accB[mi][0], 0, 0, 0);
                accB[mi][1] = __builtin_amdgcn_mfma_f32_16x16x32_bf16(af, bfr[1], accB[mi][1], 0, 0, 0);
            }
        }

        // GRU epilogue: gate row = h*256+w*64+mi*16+quad*4+g -> j=row>>2
#pragma unroll
        for (int mi = 0; mi < 4; ++mi) {
            int j = h * 64 + w * 16 + mi * 4 + quad;   // 0..127
            float4 bb = bias4[j];                      // {b_r,b_z,b_in,b_hn}
#pragma unroll
            for (int ni = 0; ni < 2; ++ni) {
                int nl = ni * 16 + lm;
                int gn = m0 + nl;
                int gc = (gn >= M) ? (M - 1) : gn;
                float g0 = accB[mi][ni][0], g1 = accB[mi][ni][1];
                float g2 = accB[mi][ni][2], g3 = accB[mi][ni][3];
                float rr = frcp(1.f + __expf(-(g0 + bb.x)));
                float zz = frcp(1.f + __expf(-(g1 + bb.y)));
                float aa = g2 + bb.z + rr * (g3 + bb.w);
                float nn = 1.f - 2.f * frcp(1.f + __expf(2.f * aa));  // tanh
                float hv = bf2f((unsigned int)hbf[(size_t)gc * HID + j]);
                Outs[nl][j - h * 64] = nn + zz * (hv - nn);
            }
        }
        __syncthreads();  // Outs complete

        // coalesced store: 32 nodes x 64 floats (this gate half)
        {
            int row = tid >> 3;              // 0..31
            int cb = (tid & 7) * 8;          // 0..56
            int node = m0 + row;
            if (node < M) {
                float* dstp = out + (size_t)node * HID + h * 64 + cb;
                *(float4*)(dstp)     = *(const float4*)&Outs[row][cb];
                *(float4*)(dstp + 4) = *(const float4*)&Outs[row][cb + 4];
            }
        }
        __syncthreads();  // protect Outs reuse by pass h=1
    }
}

// ---------------------------------------------------------------------------

extern "C" void kernel_launch(void* const* d_in, const int* in_sizes, int n_in,
                              void* d_out, int out_size, void* d_ws, size_t ws_size,
                              hipStream_t stream) {
    const float* node_states = (const float*)d_in[0];
    const int*   edge_index  = (const int*)d_in[1];
    const int*   edge_type   = (const int*)d_in[2];
    const float* edge_W      = (const float*)d_in[3];
    const float* edge_b      = (const float*)d_in[4];
    const float* w_ih        = (const float*)d_in[5];
    const float* w_hh        = (const float*)d_in[6];
    const float* b_ih        = (const float*)d_in[7];
    const float* b_hh        = (const float*)d_in[8];

    const int M = in_sizes[0] / HID;      // 50000 nodes
    const int E = in_sizes[1] / 2;        // 625000 edges
    const int N4 = M * 4;                 // 200000 (dst,type) segments
    const int* src = edge_index;
    const int* dst = edge_index + E;

    // workspace layout (~70 MB)
    char* ws = (char*)d_ws;
    size_t off = 0;
    unsigned short* hbf   = (unsigned short*)(ws + off); off += (size_t)M * HID * 2;    // 12.8MB
    float*          bias4 = (float*)(ws + off);          off += (size_t)128 * 4 * 4;    // 2KB
    unsigned short* S     = (unsigned short*)(ws + off); off += (size_t)M * 512 * 2;    // 51.2MB
    unsigned short* Wcat  = (unsigned short*)(ws + off); off += (size_t)128 * 512 * 2;  // 128KB
    unsigned short* Wgru  = (unsigned short*)(ws + off); off += (size_t)512 * 256 * 2;  // 256KB
    float*          cnt4  = (float*)(ws + off);          off += (size_t)M * 4 * 4;      // 800KB
    int* deg4     = (int*)(ws + off); off += (size_t)N4 * 4;
    int* rowptr4  = (int*)(ws + off); off += (size_t)(N4 + 1) * 4;
    int* cursor4  = (int*)(ws + off); off += (size_t)N4 * 4;
    int* blocksum = (int*)(ws + off); off += 256 * 4;
    int* blockoff = (int*)(ws + off); off += 256 * 4;
    int* csr      = (int*)(ws + off); off += (size_t)E * 4;

    const int total4 = M * HID / 4;

    BuildArgs ba;
    ba.h = node_states; ba.hbf = hbf;
    ba.W = edge_W; ba.Wc = Wcat;
    ba.wih = w_ih; ba.whh = w_hh; ba.Wg = Wgru;
    ba.bias4 = bias4; ba.bih = b_ih; ba.bhh = b_hh;
    ba.deg4 = deg4; ba.rowptr4 = rowptr4; ba.cursor4 = cursor4;
    ba.blocksum = blocksum; ba.blockoff = blockoff; ba.csr = csr;
    ba.src = src; ba.dst = dst; ba.ety = edge_type;
    ba.cnt4 = (float4*)cnt4; ba.Su = (unsigned int*)S;
    ba.M = M; ba.E = E; ba.N4 = N4; ba.total4 = total4;

    void* params[] = {&ba};
    hipLaunchCooperativeKernel((void*)build_kernel, dim3(768), dim3(256),
                               params, 0, stream);

    agg_gru<<<(M + 31) / 32, 256, 0, stream>>>(S, Wcat, Wgru, hbf, (const float4*)cnt4,
                                               edge_b, (const float4*)bias4, (float*)d_out, M);
}

// Round 6
// 292.219 us; speedup vs baseline: 3.0183x; 3.0183x over previous
//
#include <hip/hip_runtime.h>

// ---------------------------------------------------------------------------
// GGNN message passing, MI355X/gfx950.  Round 15 = R13 revert + gather_s v5.
//   R14 post-mortem: cooperative build_kernel = 662us vs 181us of separate
//   launches -- the 768-block co-residency cap serialized gather to ~16
//   nodes/wave of dependent latency chains (occ 36%, 326GB/s, VALU 3%).
//   LESSON: never throttle a latency-bound phase's parallelism for fusion.
//   agg_gru v4 (quarter-tile) also suspect (~220us by subtraction): reverted.
//   - gather_s v5: wave per (node,type) SEGMENT (200K waves, 4x R13).
//     Avg 3.1 edges/segment -> ONE predicated 8-chunk (csr round + hbu
//     round) covers ~94% of segments; no boundary snapshots.  S/cnt writes
//     identical layout (seg*64+lane == node*256+t*64+lane); agg_gru
//     untouched.
//   - agg_gru v3 verbatim R13 (92us measured): dbuf parity staging,
//     one barrier/step, phase B K=256 no barriers, fast GRU epilogue.
// Lessons: no gather-into-GEMM fusion (R6); no K-merging (R7); LDS-staged
// coalesced out stores (R5); (dst,type) CSR (R6/R9); no per-lane weight
// streaming / watch WRITE_SIZE for spill (R12); no co-op fusion of
// latency-bound phases (R14).
// ---------------------------------------------------------------------------

typedef __attribute__((ext_vector_type(8))) short short8;
typedef __attribute__((ext_vector_type(4))) float floatx4;

#define HID 128
#define NTY 4

__device__ __forceinline__ unsigned short f2bf(float f) {
    unsigned int u = __float_as_uint(f);
    unsigned int r = (u + 0x7fffu + ((u >> 16) & 1u)) >> 16;  // RNE
    return (unsigned short)r;
}
__device__ __forceinline__ float bf2f(unsigned int lo16) {
    return __uint_as_float(lo16 << 16);
}
__device__ __forceinline__ float frcp(float x) { return __builtin_amdgcn_rcpf(x); }

// ---- prep: cvt_h | pack_wcat | pack_wgru | bias4 | zero deg4 --------------

__global__ void prep_kernel(const float* __restrict__ h, unsigned short* __restrict__ hbf,
                            const float* __restrict__ W, unsigned short* __restrict__ Wc,
                            const float* __restrict__ w_ih, const float* __restrict__ w_hh,
                            unsigned short* __restrict__ Wg, float* __restrict__ bias4,
                            const float* __restrict__ b_ih, const float* __restrict__ b_hh,
                            int* __restrict__ deg4, int total4, int nb_cvt, int N4) {
    int b = blockIdx.x, tt = threadIdx.x;
    if (b < nb_cvt) {
        int i = b * 256 + tt;
        if (i < total4) {
            float4 v = ((const float4*)h)[i];
            uint2 o;
            o.x = (unsigned int)f2bf(v.x) | ((unsigned int)f2bf(v.y) << 16);
            o.y = (unsigned int)f2bf(v.z) | ((unsigned int)f2bf(v.w) << 16);
            ((uint2*)hbf)[i] = o;
        }
    } else if (b < nb_cvt + 256) {
        // Wcat[j][t*128+k] = edge_W[t][j][k]  (128 x 512)
        int idx = (b - nb_cvt) * 256 + tt;
        int j = idx >> 9, rem = idx & 511;
        int t = rem >> 7, k = rem & 127;
        Wc[idx] = f2bf(W[(t * HID + j) * HID + k]);
    } else if (b < nb_cvt + 768) {
        // Wg[512][256]: rows 4j+{0,1,2,3} = r|z|i_n|h_n; cols 0-127 agg, 128-255 h
        int idx = (b - nb_cvt - 256) * 256 + tt;
        int row = idx >> 8, k = idx & 255;
        int j = row >> 2, g = row & 3;
        float v = 0.0f;
        if (g == 0) v = (k < 128) ? w_ih[j * 128 + k]         : w_hh[j * 128 + (k - 128)];
        else if (g == 1) v = (k < 128) ? w_ih[(128 + j) * 128 + k] : w_hh[(128 + j) * 128 + (k - 128)];
        else if (g == 2) v = (k < 128) ? w_ih[(256 + j) * 128 + k] : 0.0f;
        else             v = (k < 128) ? 0.0f : w_hh[(256 + j) * 128 + (k - 128)];
        Wg[idx] = f2bf(v);
    } else if (b == nb_cvt + 768) {
        if (tt < 128) {
            float4 v;
            v.x = b_ih[tt] + b_hh[tt];
            v.y = b_ih[128 + tt] + b_hh[128 + tt];
            v.z = b_ih[256 + tt];
            v.w = b_hh[256 + tt];
            ((float4*)bias4)[tt] = v;
        }
    } else {
        int i = (b - nb_cvt - 769) * 256 + tt;
        if (i < N4) deg4[i] = 0;
    }
}

// ---- (dst,type)-segmented CSR construction (R6, verified) -----------------

__global__ void hist4_kernel(const int* __restrict__ dst, const int* __restrict__ ety,
                             int* __restrict__ deg4, int E) {
    int e = blockIdx.x * blockDim.x + threadIdx.x;
    if (e < E) atomicAdd(&deg4[dst[e] * 4 + ety[e]], 1);
}

__global__ void scan_blocks4_kernel(const int* __restrict__ deg, int* __restrict__ rowptr,
                                    int* __restrict__ blocksum, int N4) {
    __shared__ int s[256];
    int t = threadIdx.x;
    int base = blockIdx.x * 1024 + t * 4;
    int v0 = 0, v1 = 0, v2 = 0, v3 = 0;
    if (base + 3 < N4) {
        v0 = deg[base]; v1 = deg[base + 1]; v2 = deg[base + 2]; v3 = deg[base + 3];
    } else {
        if (base < N4) v0 = deg[base];
        if (base + 1 < N4) v1 = deg[base + 1];
        if (base + 2 < N4) v2 = deg[base + 2];
    }
    int sum = v0 + v1 + v2 + v3;
    s[t] = sum;
    __syncthreads();
#pragma unroll
    for (int off = 1; off < 256; off <<= 1) {
        int x = (t >= off) ? s[t - off] : 0;
        __syncthreads();
        s[t] += x;
        __syncthreads();
    }
    int ex = s[t] - sum;
    if (base < N4) rowptr[base] = ex;
    if (base + 1 < N4) rowptr[base + 1] = ex + v0;
    if (base + 2 < N4) rowptr[base + 2] = ex + v0 + v1;
    if (base + 3 < N4) rowptr[base + 3] = ex + v0 + v1 + v2;
    if (t == 255) blocksum[blockIdx.x] = s[255];
}

__global__ void scan_top_kernel(const int* __restrict__ blocksum, int* __restrict__ blockoff, int nb) {
    __shared__ int s[256];
    int t = threadIdx.x;
    int v = (t < nb) ? blocksum[t] : 0;
    s[t] = v;
    __syncthreads();
#pragma unroll
    for (int off = 1; off < 256; off <<= 1) {
        int x = (t >= off) ? s[t - off] : 0;
        __syncthreads();
        s[t] += x;
        __syncthreads();
    }
    if (t < nb) blockoff[t] = s[t] - v;
}

__global__ void finalize4_kernel(int* __restrict__ rowptr, const int* __restrict__ blockoff,
                                 int* __restrict__ cursor, int N4, int E) {
    int i = blockIdx.x * blockDim.x + threadIdx.x;
    if (i >= N4) return;
    int r = rowptr[i] + blockoff[i >> 10];
    rowptr[i] = r;
    cursor[i] = r;
    if (i == 0) rowptr[N4] = E;  // sentinel
}

__global__ void fill4_kernel(const int* __restrict__ src, const int* __restrict__ dst,
                             const int* __restrict__ ety, int* __restrict__ cursor,
                             int* __restrict__ csr, int E) {
    int e = blockIdx.x * blockDim.x + threadIdx.x;
    if (e >= E) return;
    int pos = atomicAdd(&cursor[dst[e] * 4 + ety[e]], 1);
    csr[pos] = src[e];
}

// ---- gather_s v5: one wave per (node,type) segment ------------------------
// seg = node*4 + t.  Wave sums its own segment (avg 3.1 edges) with ONE
// predicated 8-chunk per round; no boundary snapshots.  Lane owns cols
// {2l,2l+1}.  S row = Su[seg*64+lane] (== node*256+t*64+lane, same layout
// as R13).  cnt[seg] = segment length.

__global__ void gather_s_kernel(const int* __restrict__ rowptr4, const int* __restrict__ csr,
                                const unsigned int* __restrict__ hbu,
                                float* __restrict__ cnt, unsigned int* __restrict__ Su, int N4) {
    int seg = blockIdx.x * (blockDim.x >> 6) + (threadIdx.x >> 6);
    if (seg >= N4) return;
    int lane = threadIdx.x & 63;
    int b0 = __builtin_amdgcn_readfirstlane(rowptr4[seg]);
    int b1 = __builtin_amdgcn_readfirstlane(rowptr4[seg + 1]);  // sentinel-backed

    float s0 = 0.f, s1 = 0.f;
    for (int base = b0; base < b1; base += 8) {
        int rem = b1 - base;                     // wave-uniform
        int p[8];
        unsigned int u[8];
#pragma unroll
        for (int i = 0; i < 8; ++i) if (i < rem) p[i] = csr[base + i];
#pragma unroll
        for (int i = 0; i < 8; ++i) if (i < rem) u[i] = hbu[(size_t)p[i] * 64 + lane];
#pragma unroll
        for (int i = 0; i < 8; ++i) {
            if (i < rem) {
                s0 += bf2f(u[i] & 0xffffu);
                s1 += bf2f(u[i] >> 16);
            }
        }
    }

    Su[(size_t)seg * 64 + lane] = (unsigned int)f2bf(s0) | ((unsigned int)f2bf(s1) << 16);
    if (lane == 0) cnt[seg] = (float)(b1 - b0);
}

// ---- agg_gru v3 (verbatim R13, 92us measured): fused GEMM -> GRU ----------
// 64-node tile, 512 threads (8 waves).
// Phase A: wave w owns agg cols [w*16,+16); K=512 in 4 BK=128 steps.
//   Step c: (issue global loads for c+1) -> ds_write regs(c) -> barrier ->
//   16 MFMA from Sb[c&1].  ONE barrier/step (buffer parity covers WAR).
// Handoff: agg(+cnt.eb) -> Xagg[64][136] bf16; barrier.
// Phase B: no barriers.  K=256: ss 0-3 agg from LDS, ss 4-7 h direct from
//   hbf (L1/L2-hot).  Wg frags in-loop from L2.  accB[4][4] gates packed.
// Epilogue: fast sigmoid/tanh; hv direct from hbf; f32 Outs tile (overlays
//   Sb after the handoff barrier); coalesced float4 stores.

__global__ __launch_bounds__(512, 4) void agg_gru(const unsigned short* __restrict__ S,
                                                  const unsigned short* __restrict__ Wc,
                                                  const unsigned short* __restrict__ Wg,
                                                  const unsigned short* __restrict__ hbf,
                                                  const float4* __restrict__ cnt4,
                                                  const float* __restrict__ eb,
                                                  const float4* __restrict__ bias4,
                                                  float* __restrict__ out, int M) {
    __shared__ __align__(16) unsigned char smem[52224];
    typedef unsigned short row136[136];
    row136* Sb0  = (row136*)smem;                  // [64][136]  17408B
    row136* Sb1  = (row136*)(smem + 17408);        // [64][136]  17408B
    row136* Xagg = (row136*)(smem + 34816);        // [64][136]  17408B
    float (*Outs)[132] = (float (*)[132])smem;     // overlay on Sb (33792B)

    const int tid = threadIdx.x;
    const int m0 = blockIdx.x * 64;
    const int lane = tid & 63, w = tid >> 6;
    const int lm = lane & 15, quad = lane >> 4;

    // staging geometry: thread stages rows {r0, r0+32} x 8 shorts at col sc
    const int r0 = tid >> 4, sc = (tid & 15) * 8;
    const int gA = m0 + r0, gB = m0 + 32 + r0;
    const bool vA = gA < M, vB = gB < M;
    const unsigned short* SpA = S + (size_t)(vA ? gA : 0) * 512 + sc;
    const unsigned short* SpB = S + (size_t)(vB ? gB : 0) * 512 + sc;
    const uint4 Z = {0u, 0u, 0u, 0u};

    uint4 c0v = vA ? *(const uint4*)SpA : Z;     // chunk c=0 in regs
    uint4 c1v = vB ? *(const uint4*)SpB : Z;

    floatx4 accA[4];
#pragma unroll
    for (int a = 0; a < 4; ++a) accA[a] = (floatx4){0.f, 0.f, 0.f, 0.f};

#pragma unroll 1
    for (int c = 0; c < 4; ++c) {
        uint4 n0v = Z, n1v = Z;
        if (c < 3) {                              // issue next-step loads EARLY
            n0v = vA ? *(const uint4*)(SpA + (c + 1) * 128) : Z;
            n1v = vB ? *(const uint4*)(SpB + (c + 1) * 128) : Z;
        }
        row136* buf = (c & 1) ? Sb1 : Sb0;
        *(uint4*)&buf[r0][sc] = c0v;
        *(uint4*)&buf[32 + r0][sc] = c1v;
        __syncthreads();                          // staging visible
#pragma unroll
        for (int ss = 0; ss < 4; ++ss) {
            short8 bw = *(const short8*)(Wc + (size_t)(w * 16 + lm) * 512 + c * 128 + ss * 32 + quad * 8);
#pragma unroll
            for (int mi = 0; mi < 4; ++mi) {
                short8 av = *(const short8*)&buf[mi * 16 + lm][ss * 32 + quad * 8];
                accA[mi] = __builtin_amdgcn_mfma_f32_16x16x32_bf16(av, bw, accA[mi], 0, 0, 0);
            }
        }
        c0v = n0v; c1v = n1v;
        // no trailing barrier: next step writes the OTHER buffer; the write
        // two steps ahead is ordered by the intervening step's barrier.
    }

    // handoff: agg(+cnt.eb) -> Xagg (bf16).  D: row nl=mi*16+quad*4+r,
    // col j=w*16+lm  (harness-verified mapping).
    {
        int j = w * 16 + lm;
        float e0 = eb[j], e1 = eb[HID + j], e2 = eb[2 * HID + j], e3 = eb[3 * HID + j];
#pragma unroll
        for (int mi = 0; mi < 4; ++mi) {
#pragma unroll
            for (int r = 0; r < 4; ++r) {
                int nl = mi * 16 + quad * 4 + r;
                int gn = m0 + nl;
                if (gn >= M) gn = M - 1;
                float4 c4 = cnt4[gn];
                float v = accA[mi][r] + c4.x * e0 + c4.y * e1 + c4.z * e2 + c4.w * e3;
                Xagg[nl][j] = f2bf(v);
            }
        }
    }
    __syncthreads();  // Xagg complete; all waves past phase A (Sb dead)

    // ---- phase B: gates[512 x 64] = Wg @ [agg|h]^T, K=256, no barriers ----
    floatx4 accB[4][4];
#pragma unroll
    for (int a = 0; a < 4; ++a)
#pragma unroll
        for (int b = 0; b < 4; ++b) accB[a][b] = (floatx4){0.f, 0.f, 0.f, 0.f};

#pragma unroll
    for (int ss = 0; ss < 8; ++ss) {
        short8 bfr[4];
#pragma unroll
        for (int ni = 0; ni < 4; ++ni) {
            if (ss < 4) {
                bfr[ni] = *(const short8*)&Xagg[ni * 16 + lm][ss * 32 + quad * 8];
            } else {
                int gr = m0 + ni * 16 + lm;
                if (gr >= M) gr = M - 1;
                bfr[ni] = *(const short8*)(hbf + (size_t)gr * HID + (ss - 4) * 32 + quad * 8);
            }
        }
        short8 af[4];
#pragma unroll
        for (int mi = 0; mi < 4; ++mi)
            af[mi] = *(const short8*)(Wg + (size_t)(w * 64 + mi * 16 + lm) * 256 + ss * 32 + quad * 8);
#pragma unroll
        for (int mi = 0; mi < 4; ++mi)
#pragma unroll
            for (int ni = 0; ni < 4; ++ni)
                accB[mi][ni] = __builtin_amdgcn_mfma_f32_16x16x32_bf16(af[mi], bfr[ni], accB[mi][ni], 0, 0, 0);
    }

    // GRU epilogue -> Outs.  gate row = w*64+mi*16+quad*4+g -> j = row>>2,
    // g = reg (harness-verified).
#pragma unroll
    for (int mi = 0; mi < 4; ++mi) {
        int j = w * 16 + mi * 4 + quad;   // 0..127
        float4 bb = bias4[j];             // {b_r, b_z, b_in, b_hn}
#pragma unroll
        for (int ni = 0; ni < 4; ++ni) {
            int nl = ni * 16 + lm;
            int gn = m0 + nl;
            int gc = (gn >= M) ? (M - 1) : gn;
            float g0 = accB[mi][ni][0], g1 = accB[mi][ni][1];
            float g2 = accB[mi][ni][2], g3 = accB[mi][ni][3];
            float rr = frcp(1.f + __expf(-(g0 + bb.x)));
            float zz = frcp(1.f + __expf(-(g1 + bb.y)));
            float aa = g2 + bb.z + rr * (g3 + bb.w);
            float nn = 1.f - 2.f * frcp(1.f + __expf(2.f * aa));  // tanh
            float hv = bf2f((unsigned int)hbf[(size_t)gc * HID + j]);
            Outs[nl][j] = nn + zz * (hv - nn);
        }
    }
    __syncthreads();  // Outs complete (Sb region; all waves past phase A)

    // coalesced store: 64 nodes x 128 floats (128B per 8 lanes)
    {
        int row = tid >> 3;              // 0..63
        int cb = (tid & 7) * 16;         // 0..112
        int node = m0 + row;
        if (node < M) {
            float* dstp = out + (size_t)node * HID + cb;
#pragma unroll
            for (int i = 0; i < 4; ++i)
                *(float4*)(dstp + i * 4) = *(const float4*)&Outs[row][cb + i * 4];
        }
    }
}

// ---------------------------------------------------------------------------

extern "C" void kernel_launch(void* const* d_in, const int* in_sizes, int n_in,
                              void* d_out, int out_size, void* d_ws, size_t ws_size,
                              hipStream_t stream) {
    const float* node_states = (const float*)d_in[0];
    const int*   edge_index  = (const int*)d_in[1];
    const int*   edge_type   = (const int*)d_in[2];
    const float* edge_W      = (const float*)d_in[3];
    const float* edge_b      = (const float*)d_in[4];
    const float* w_ih        = (const float*)d_in[5];
    const float* w_hh        = (const float*)d_in[6];
    const float* b_ih        = (const float*)d_in[7];
    const float* b_hh        = (const float*)d_in[8];

    const int M = in_sizes[0] / HID;      // 50000 nodes
    const int E = in_sizes[1] / 2;        // 625000 edges
    const int N4 = M * 4;                 // 200000 (dst,type) segments
    const int* src = edge_index;
    const int* dst = edge_index + E;

    // workspace layout (~70 MB)
    char* ws = (char*)d_ws;
    size_t off = 0;
    unsigned short* hbf   = (unsigned short*)(ws + off); off += (size_t)M * HID * 2;    // 12.8MB
    float*          bias4 = (float*)(ws + off);          off += (size_t)128 * 4 * 4;    // 2KB
    unsigned short* S     = (unsigned short*)(ws + off); off += (size_t)M * 512 * 2;    // 51.2MB
    unsigned short* Wcat  = (unsigned short*)(ws + off); off += (size_t)128 * 512 * 2;  // 128KB
    unsigned short* Wgru  = (unsigned short*)(ws + off); off += (size_t)512 * 256 * 2;  // 256KB
    float*          cnt4  = (float*)(ws + off);          off += (size_t)M * 4 * 4;      // 800KB
    int* deg4     = (int*)(ws + off); off += (size_t)N4 * 4;
    int* rowptr4  = (int*)(ws + off); off += (size_t)(N4 + 1) * 4;
    int* cursor4  = (int*)(ws + off); off += (size_t)N4 * 4;
    int* blocksum = (int*)(ws + off); off += 256 * 4;
    int* blockoff = (int*)(ws + off); off += 256 * 4;
    int* csr      = (int*)(ws + off); off += (size_t)E * 4;

    const int total4 = M * HID / 4;
    const int nb_cvt = (total4 + 255) / 256;     // 6250
    const int nb_zero = (N4 + 255) / 256;        // 782
    const int nb_scan = (N4 + 1023) / 1024;      // 196 <= 256

    prep_kernel<<<nb_cvt + 769 + nb_zero, 256, 0, stream>>>(
        node_states, hbf, edge_W, Wcat, w_ih, w_hh, Wgru, bias4, b_ih, b_hh,
        deg4, total4, nb_cvt, N4);

    hist4_kernel<<<(E + 255) / 256, 256, 0, stream>>>(dst, edge_type, deg4, E);
    scan_blocks4_kernel<<<nb_scan, 256, 0, stream>>>(deg4, rowptr4, blocksum, N4);
    scan_top_kernel<<<1, 256, 0, stream>>>(blocksum, blockoff, nb_scan);
    finalize4_kernel<<<(N4 + 255) / 256, 256, 0, stream>>>(rowptr4, blockoff, cursor4, N4, E);
    fill4_kernel<<<(E + 255) / 256, 256, 0, stream>>>(src, dst, edge_type, cursor4, csr, E);

    // v5: one wave per (node,type) segment -> N4 waves, 4 per 256-block
    gather_s_kernel<<<(N4 + 3) / 4, 256, 0, stream>>>(rowptr4, csr, (const unsigned int*)hbf,
                                                      (float*)cnt4, (unsigned int*)S, N4);

    agg_gru<<<(M + 63) / 64, 512, 0, stream>>>(S, Wcat, Wgru, hbf, (const float4*)cnt4,
                                               edge_b, (const float4*)bias4, (float*)d_out, M);
}

// Round 7
// 244.609 us; speedup vs baseline: 3.6058x; 1.1946x over previous
//
#include <hip/hip_runtime.h>

// ---------------------------------------------------------------------------
// GGNN message passing, MI355X/gfx950.  Round 16 = R13 + agg_gru v5.
//   R15 post-mortem: gather v5 (wave/segment) regressed ~19us -> revert to
//   v4 (wave/node).  agg_gru stable at 92us, MfmaUtil 8%, 0.7TB/s: ~85% of
//   cycles issue nothing.  The one never-varied factor across R0-R15: the
//   WEIGHT operand was always an in-loop global load (MLP=1..4) on the MFMA
//   critical path; activations were always LDS-staged.  v5 stages BOTH:
//     LDS = Sreg[64x128] + Wreg[128x128] + Xagg[64x128], XOR-swizzled
//     (grp ^= row&7; fragment reads 2-way = free), exactly 64KB -> 2 blk/CU.
//     Phase A per c: bulk-stage S-slice+Wc-slice -> bar -> 16 MFMA (LDS
//     only) -> bar.  Phase B: hbf tile in Sreg; per 128-gate-row chunk
//     stage Wg 32KB x2 -> MFMA LDS-only; GRU math in regs; f32 Outs
//     overlay on Wreg; coalesced stores.
// Lessons: no gather-into-GEMM fusion (R6); no K-merging (R7); LDS-staged
// coalesced out stores (R5); (dst,type) CSR (R6/R9); no per-lane weight
// streaming / watch WRITE_SIZE for spill (R12); no co-op fusion of
// latency-bound phases (R14); wave-per-node gather beats wave-per-segment
// (R15).
// ---------------------------------------------------------------------------

typedef __attribute__((ext_vector_type(8))) short short8;
typedef __attribute__((ext_vector_type(4))) float floatx4;

#define HID 128
#define NTY 4

__device__ __forceinline__ unsigned short f2bf(float f) {
    unsigned int u = __float_as_uint(f);
    unsigned int r = (u + 0x7fffu + ((u >> 16) & 1u)) >> 16;  // RNE
    return (unsigned short)r;
}
__device__ __forceinline__ float bf2f(unsigned int lo16) {
    return __uint_as_float(lo16 << 16);
}
__device__ __forceinline__ float frcp(float x) { return __builtin_amdgcn_rcpf(x); }

// ---- prep: cvt_h | pack_wcat | pack_wgru | bias4 | zero deg4 --------------

__global__ void prep_kernel(const float* __restrict__ h, unsigned short* __restrict__ hbf,
                            const float* __restrict__ W, unsigned short* __restrict__ Wc,
                            const float* __restrict__ w_ih, const float* __restrict__ w_hh,
                            unsigned short* __restrict__ Wg, float* __restrict__ bias4,
                            const float* __restrict__ b_ih, const float* __restrict__ b_hh,
                            int* __restrict__ deg4, int total4, int nb_cvt, int N4) {
    int b = blockIdx.x, tt = threadIdx.x;
    if (b < nb_cvt) {
        int i = b * 256 + tt;
        if (i < total4) {
            float4 v = ((const float4*)h)[i];
            uint2 o;
            o.x = (unsigned int)f2bf(v.x) | ((unsigned int)f2bf(v.y) << 16);
            o.y = (unsigned int)f2bf(v.z) | ((unsigned int)f2bf(v.w) << 16);
            ((uint2*)hbf)[i] = o;
        }
    } else if (b < nb_cvt + 256) {
        // Wcat[j][t*128+k] = edge_W[t][j][k]  (128 x 512)
        int idx = (b - nb_cvt) * 256 + tt;
        int j = idx >> 9, rem = idx & 511;
        int t = rem >> 7, k = rem & 127;
        Wc[idx] = f2bf(W[(t * HID + j) * HID + k]);
    } else if (b < nb_cvt + 768) {
        // Wg[512][256]: rows 4j+{0,1,2,3} = r|z|i_n|h_n; cols 0-127 agg, 128-255 h
        int idx = (b - nb_cvt - 256) * 256 + tt;
        int row = idx >> 8, k = idx & 255;
        int j = row >> 2, g = row & 3;
        float v = 0.0f;
        if (g == 0) v = (k < 128) ? w_ih[j * 128 + k]         : w_hh[j * 128 + (k - 128)];
        else if (g == 1) v = (k < 128) ? w_ih[(128 + j) * 128 + k] : w_hh[(128 + j) * 128 + (k - 128)];
        else if (g == 2) v = (k < 128) ? w_ih[(256 + j) * 128 + k] : 0.0f;
        else             v = (k < 128) ? 0.0f : w_hh[(256 + j) * 128 + (k - 128)];
        Wg[idx] = f2bf(v);
    } else if (b == nb_cvt + 768) {
        if (tt < 128) {
            float4 v;
            v.x = b_ih[tt] + b_hh[tt];
            v.y = b_ih[128 + tt] + b_hh[128 + tt];
            v.z = b_ih[256 + tt];
            v.w = b_hh[256 + tt];
            ((float4*)bias4)[tt] = v;
        }
    } else {
        int i = (b - nb_cvt - 769) * 256 + tt;
        if (i < N4) deg4[i] = 0;
    }
}

// ---- (dst,type)-segmented CSR construction (R6, verified) -----------------

__global__ void hist4_kernel(const int* __restrict__ dst, const int* __restrict__ ety,
                             int* __restrict__ deg4, int E) {
    int e = blockIdx.x * blockDim.x + threadIdx.x;
    if (e < E) atomicAdd(&deg4[dst[e] * 4 + ety[e]], 1);
}

__global__ void scan_blocks4_kernel(const int* __restrict__ deg, int* __restrict__ rowptr,
                                    int* __restrict__ blocksum, int N4) {
    __shared__ int s[256];
    int t = threadIdx.x;
    int base = blockIdx.x * 1024 + t * 4;
    int v0 = 0, v1 = 0, v2 = 0, v3 = 0;
    if (base + 3 < N4) {
        v0 = deg[base]; v1 = deg[base + 1]; v2 = deg[base + 2]; v3 = deg[base + 3];
    } else {
        if (base < N4) v0 = deg[base];
        if (base + 1 < N4) v1 = deg[base + 1];
        if (base + 2 < N4) v2 = deg[base + 2];
    }
    int sum = v0 + v1 + v2 + v3;
    s[t] = sum;
    __syncthreads();
#pragma unroll
    for (int off = 1; off < 256; off <<= 1) {
        int x = (t >= off) ? s[t - off] : 0;
        __syncthreads();
        s[t] += x;
        __syncthreads();
    }
    int ex = s[t] - sum;
    if (base < N4) rowptr[base] = ex;
    if (base + 1 < N4) rowptr[base + 1] = ex + v0;
    if (base + 2 < N4) rowptr[base + 2] = ex + v0 + v1;
    if (base + 3 < N4) rowptr[base + 3] = ex + v0 + v1 + v2;
    if (t == 255) blocksum[blockIdx.x] = s[255];
}

__global__ void scan_top_kernel(const int* __restrict__ blocksum, int* __restrict__ blockoff, int nb) {
    __shared__ int s[256];
    int t = threadIdx.x;
    int v = (t < nb) ? blocksum[t] : 0;
    s[t] = v;
    __syncthreads();
#pragma unroll
    for (int off = 1; off < 256; off <<= 1) {
        int x = (t >= off) ? s[t - off] : 0;
        __syncthreads();
        s[t] += x;
        __syncthreads();
    }
    if (t < nb) blockoff[t] = s[t] - v;
}

__global__ void finalize4_kernel(int* __restrict__ rowptr, const int* __restrict__ blockoff,
                                 int* __restrict__ cursor, int N4, int E) {
    int i = blockIdx.x * blockDim.x + threadIdx.x;
    if (i >= N4) return;
    int r = rowptr[i] + blockoff[i >> 10];
    rowptr[i] = r;
    cursor[i] = r;
    if (i == 0) rowptr[N4] = E;  // sentinel
}

__global__ void fill4_kernel(const int* __restrict__ src, const int* __restrict__ dst,
                             const int* __restrict__ ety, int* __restrict__ cursor,
                             int* __restrict__ csr, int E) {
    int e = blockIdx.x * blockDim.x + threadIdx.x;
    if (e >= E) return;
    int pos = atomicAdd(&cursor[dst[e] * 4 + ety[e]], 1);
    csr[pos] = src[e];
}

// ---- gather_s v4 (R13, measured-best): flat MLP-8 chunks + snapshots ------

__global__ void gather_s_kernel(const int* __restrict__ rowptr4, const int* __restrict__ csr,
                                const unsigned int* __restrict__ hbu,
                                float4* __restrict__ cnt4, unsigned int* __restrict__ Su, int N) {
    int w = blockIdx.x * (blockDim.x >> 6) + (threadIdx.x >> 6);
    if (w >= N) return;
    int lane = threadIdx.x & 63;
    int b0 = __builtin_amdgcn_readfirstlane(rowptr4[w * 4]);
    int b1 = __builtin_amdgcn_readfirstlane(rowptr4[w * 4 + 1]);
    int b2 = __builtin_amdgcn_readfirstlane(rowptr4[w * 4 + 2]);
    int b3 = __builtin_amdgcn_readfirstlane(rowptr4[w * 4 + 3]);
    int b4 = __builtin_amdgcn_readfirstlane(rowptr4[w * 4 + 4]);  // sentinel-backed

    float s0 = 0.f, s1 = 0.f;
    float sn0[3], sn1[3];

    int e = b0;
    while (e + 8 <= b4) {
        int p[8];
        unsigned int u[8];
#pragma unroll
        for (int i = 0; i < 8; ++i) p[i] = csr[e + i];
#pragma unroll
        for (int i = 0; i < 8; ++i) u[i] = hbu[(size_t)p[i] * 64 + lane];
#pragma unroll
        for (int i = 0; i < 8; ++i) {
            int idx = e + i;
            if (idx == b1) { sn0[0] = s0; sn1[0] = s1; }
            if (idx == b2) { sn0[1] = s0; sn1[1] = s1; }
            if (idx == b3) { sn0[2] = s0; sn1[2] = s1; }
            s0 += bf2f(u[i] & 0xffffu);
            s1 += bf2f(u[i] >> 16);
        }
        e += 8;
    }
    {   // tail: 0..7 edges, uniform predication
        int rem = b4 - e;
        int p[7];
        unsigned int u[7];
#pragma unroll
        for (int i = 0; i < 7; ++i) if (i < rem) p[i] = csr[e + i];
#pragma unroll
        for (int i = 0; i < 7; ++i) if (i < rem) u[i] = hbu[(size_t)p[i] * 64 + lane];
#pragma unroll
        for (int i = 0; i < 7; ++i) {
            if (i < rem) {
                int idx = e + i;
                if (idx == b1) { sn0[0] = s0; sn1[0] = s1; }
                if (idx == b2) { sn0[1] = s0; sn1[1] = s1; }
                if (idx == b3) { sn0[2] = s0; sn1[2] = s1; }
                s0 += bf2f(u[i] & 0xffffu);
                s1 += bf2f(u[i] >> 16);
            }
        }
    }
    if (b1 == b4) { sn0[0] = s0; sn1[0] = s1; }
    if (b2 == b4) { sn0[1] = s0; sn1[1] = s1; }
    if (b3 == b4) { sn0[2] = s0; sn1[2] = s1; }

    size_t base = (size_t)w * 256 + lane;
    float a0, a1, p0 = 0.f, p1 = 0.f;
#pragma unroll
    for (int t = 0; t < 4; ++t) {
        float c0 = (t < 3) ? sn0[t] : s0;
        float c1 = (t < 3) ? sn1[t] : s1;
        a0 = c0 - p0; a1 = c1 - p1;
        p0 = c0; p1 = c1;
        Su[base + t * 64] = (unsigned int)f2bf(a0) | ((unsigned int)f2bf(a1) << 16);
    }
    if (lane == 0)
        cnt4[w] = make_float4((float)(b1 - b0), (float)(b2 - b1),
                              (float)(b3 - b2), (float)(b4 - b3));
}

// ---- agg_gru v5: BOTH operands LDS-staged, XOR-swizzled, 64KB -------------
// 64-node tile, 512 threads (8 waves), 2 blocks/CU.
// Swizzle: 128-short rows; 8-short group g stored at g^(row&7).
// Phase A (c=0..3): stage Sreg[64][128] (S c-slice) + Wreg[128][128]
//   (Wc c-slice) -> bar -> 16 MFMA (all operands LDS) -> bar.
// Handoff: agg(+cnt.eb) -> Xagg (swizzled scalar writes); bar.
// Phase B: stage hbf tile -> Sreg once; per gc (0..3, 128 gate rows):
//   {stage Wg(gc,kc=0) -> bar -> 16 MFMA (B=Xagg) -> bar ->
//    stage Wg(gc,kc=1) -> bar -> 16 MFMA (B=Sreg/hbf) -> GRU math -> bar}.
// Epilogue: fin[4][4] regs -> f32 Outs overlay on Wreg (swizzled) ->
//   coalesced float4 stores.

__global__ __launch_bounds__(512, 4) void agg_gru(const unsigned short* __restrict__ S,
                                                  const unsigned short* __restrict__ Wc,
                                                  const unsigned short* __restrict__ Wg,
                                                  const unsigned short* __restrict__ hbf,
                                                  const float4* __restrict__ cnt4,
                                                  const float* __restrict__ eb,
                                                  const float4* __restrict__ bias4,
                                                  float* __restrict__ out, int M) {
    __shared__ __align__(16) unsigned short Sreg[64 * 128];    // 16384B
    __shared__ __align__(16) unsigned short Wreg[128 * 128];   // 32768B
    __shared__ __align__(16) unsigned short Xagg[64 * 128];    // 16384B
    float* OutsF = (float*)Wreg;                               // overlay, 32768B

    const int tid = threadIdx.x;
    const int m0 = blockIdx.x * 64;
    const int lane = tid & 63, w = tid >> 6;
    const int lm = lane & 15, quad = lane >> 4;
    const uint4 Z = {0u, 0u, 0u, 0u};

    // staging geometry: 16 threads per row-slice, 8 shorts each
    const int sr = tid >> 4;          // 0..31
    const int sg = tid & 15;          // group 0..15
    // S/hbf staging rows: sr and 32+sr ; Wc/Wg staging rows: sr+{0,32,64,96}

    // ---- phase A ----
    floatx4 accA[4];
#pragma unroll
    for (int a = 0; a < 4; ++a) accA[a] = (floatx4){0.f, 0.f, 0.f, 0.f};

#pragma unroll 1
    for (int c = 0; c < 4; ++c) {
        // stage S c-slice -> Sreg (swizzled)
        {
            int gA = m0 + sr, gB = m0 + 32 + sr;
            uint4 vA = (gA < M) ? *(const uint4*)(S + (size_t)gA * 512 + c * 128 + sg * 8) : Z;
            uint4 vB = (gB < M) ? *(const uint4*)(S + (size_t)gB * 512 + c * 128 + sg * 8) : Z;
            *(uint4*)&Sreg[sr * 128 + ((sg ^ (sr & 7)) << 3)] = vA;
            *(uint4*)&Sreg[(32 + sr) * 128 + ((sg ^ (sr & 7)) << 3)] = vB;
        }
        // stage Wc c-slice (128 j-rows x 128 k) -> Wreg (swizzled)
#pragma unroll
        for (int p = 0; p < 4; ++p) {
            int j = p * 32 + sr;
            uint4 v = *(const uint4*)(Wc + (size_t)j * 512 + c * 128 + sg * 8);
            *(uint4*)&Wreg[j * 128 + ((sg ^ (j & 7)) << 3)] = v;
        }
        __syncthreads();
#pragma unroll
        for (int ss = 0; ss < 4; ++ss) {
            int g = ss * 4 + quad;
            short8 bw = *(const short8*)&Wreg[(w * 16 + lm) * 128 + ((g ^ (lm & 7)) << 3)];
#pragma unroll
            for (int mi = 0; mi < 4; ++mi) {
                short8 av = *(const short8*)&Sreg[(mi * 16 + lm) * 128 + ((g ^ (lm & 7)) << 3)];
                accA[mi] = __builtin_amdgcn_mfma_f32_16x16x32_bf16(av, bw, accA[mi], 0, 0, 0);
            }
        }
        __syncthreads();   // WAR: next c overwrites Sreg/Wreg
    }

    // handoff: agg(+cnt.eb) -> Xagg (swizzled scalar writes)
    {
        int j = w * 16 + lm;
        float e0 = eb[j], e1 = eb[HID + j], e2 = eb[2 * HID + j], e3 = eb[3 * HID + j];
        int jg = j >> 3, jr = j & 7;
#pragma unroll
        for (int mi = 0; mi < 4; ++mi) {
#pragma unroll
            for (int r = 0; r < 4; ++r) {
                int nl = mi * 16 + quad * 4 + r;
                int gn = m0 + nl;
                if (gn >= M) gn = M - 1;
                float4 c4 = cnt4[gn];
                float v = accA[mi][r] + c4.x * e0 + c4.y * e1 + c4.z * e2 + c4.w * e3;
                Xagg[nl * 128 + ((jg ^ (nl & 7)) << 3) + jr] = f2bf(v);
            }
        }
    }
    __syncthreads();  // Xagg complete; Sreg/Wreg free

    // stage hbf tile -> Sreg (swizzled) for phase B
    {
        int gA = m0 + sr, gB = m0 + 32 + sr;
        uint4 vA = (gA < M) ? *(const uint4*)(hbf + (size_t)gA * HID + sg * 8) : Z;
        uint4 vB = (gB < M) ? *(const uint4*)(hbf + (size_t)gB * HID + sg * 8) : Z;
        *(uint4*)&Sreg[sr * 128 + ((sg ^ (sr & 7)) << 3)] = vA;
        *(uint4*)&Sreg[(32 + sr) * 128 + ((sg ^ (sr & 7)) << 3)] = vB;
        // no barrier needed yet: barrier inside gc loop before first MFMA
    }

    // ---- phase B: 4 gate-row chunks of 128 ----
    float fin[4][4];   // [gc][ni]

#pragma unroll 1
    for (int gc = 0; gc < 4; ++gc) {
        floatx4 accB[4];
#pragma unroll
        for (int a = 0; a < 4; ++a) accB[a] = (floatx4){0.f, 0.f, 0.f, 0.f};

#pragma unroll 1
        for (int kc = 0; kc < 2; ++kc) {
            // stage Wg slice (rows gc*128..+128, cols kc*128..+128)
#pragma unroll
            for (int p = 0; p < 4; ++p) {
                int rr = p * 32 + sr;                    // 0..127 within slice
                int grow = gc * 128 + rr;
                uint4 v = *(const uint4*)(Wg + (size_t)grow * 256 + kc * 128 + sg * 8);
                *(uint4*)&Wreg[rr * 128 + ((sg ^ (rr & 7)) << 3)] = v;
            }
            __syncthreads();  // staging visible (also covers hbf stage at gc=0,kc=0)
#pragma unroll
            for (int ss = 0; ss < 4; ++ss) {
                int g = ss * 4 + quad;
                short8 af = *(const short8*)&Wreg[(w * 16 + lm) * 128 + ((g ^ (lm & 7)) << 3)];
#pragma unroll
                for (int ni = 0; ni < 4; ++ni) {
                    const unsigned short* bsrc = kc ? Sreg : Xagg;
                    short8 bfr = *(const short8*)&bsrc[(ni * 16 + lm) * 128 + ((g ^ (lm & 7)) << 3)];
                    accB[ni] = __builtin_amdgcn_mfma_f32_16x16x32_bf16(af, bfr, accB[ni], 0, 0, 0);
                }
            }
            __syncthreads();  // WAR before next Wg stage
        }

        // GRU math for this chunk.  D row (rel) = w*16+quad*4+r ->
        // j = gc*32 + w*4 + quad, gate g = r.  D col = node = ni*16+lm.
        {
            int j = gc * 32 + w * 4 + quad;
            float4 bb = bias4[j];
            int jg = j >> 3, jr = j & 7;
#pragma unroll
            for (int ni = 0; ni < 4; ++ni) {
                int nl = ni * 16 + lm;
                float g0 = accB[ni][0], g1 = accB[ni][1];
                float g2 = accB[ni][2], g3 = accB[ni][3];
                float rr = frcp(1.f + __expf(-(g0 + bb.x)));
                float zz = frcp(1.f + __expf(-(g1 + bb.y)));
                float aa = g2 + bb.z + rr * (g3 + bb.w);
                float nn = 1.f - 2.f * frcp(1.f + __expf(2.f * aa));  // tanh
                float hv = bf2f((unsigned int)Sreg[nl * 128 + ((jg ^ (nl & 7)) << 3) + jr]);
                fin[gc][ni] = nn + zz * (hv - nn);
            }
        }
    }
    __syncthreads();  // all Wreg reads done -> Outs overlay safe

    // write fin -> Outs (f32, swizzled: 4-float group gq at gq^(row&7))
#pragma unroll
    for (int gc = 0; gc < 4; ++gc) {
        int j = gc * 32 + w * 4 + quad;
        int gq = j >> 2, jr = j & 3;
#pragma unroll
        for (int ni = 0; ni < 4; ++ni) {
            int nl = ni * 16 + lm;
            OutsF[nl * 128 + ((gq ^ (nl & 7)) << 2) + jr] = fin[gc][ni];
        }
    }
    __syncthreads();

    // coalesced store: 64 nodes x 128 floats
    {
        int row = tid >> 3;              // 0..63
        int cb = (tid & 7) * 16;         // 0..112
        int node = m0 + row;
        if (node < M) {
            float* dstp = out + (size_t)node * HID + cb;
#pragma unroll
            for (int i = 0; i < 4; ++i) {
                int gq = (cb >> 2) + i;
                *(float4*)(dstp + i * 4) = *(const float4*)&OutsF[row * 128 + ((gq ^ (row & 7)) << 2)];
            }
        }
    }
}

// ---------------------------------------------------------------------------

extern "C" void kernel_launch(void* const* d_in, const int* in_sizes, int n_in,
                              void* d_out, int out_size, void* d_ws, size_t ws_size,
                              hipStream_t stream) {
    const float* node_states = (const float*)d_in[0];
    const int*   edge_index  = (const int*)d_in[1];
    const int*   edge_type   = (const int*)d_in[2];
    const float* edge_W      = (const float*)d_in[3];
    const float* edge_b      = (const float*)d_in[4];
    const float* w_ih        = (const float*)d_in[5];
    const float* w_hh        = (const float*)d_in[6];
    const float* b_ih        = (const float*)d_in[7];
    const float* b_hh        = (const float*)d_in[8];

    const int M = in_sizes[0] / HID;      // 50000 nodes
    const int E = in_sizes[1] / 2;        // 625000 edges
    const int N4 = M * 4;                 // 200000 (dst,type) segments
    const int* src = edge_index;
    const int* dst = edge_index + E;

    // workspace layout (~70 MB)
    char* ws = (char*)d_ws;
    size_t off = 0;
    unsigned short* hbf   = (unsigned short*)(ws + off); off += (size_t)M * HID * 2;    // 12.8MB
    float*          bias4 = (float*)(ws + off);          off += (size_t)128 * 4 * 4;    // 2KB
    unsigned short* S     = (unsigned short*)(ws + off); off += (size_t)M * 512 * 2;    // 51.2MB
    unsigned short* Wcat  = (unsigned short*)(ws + off); off += (size_t)128 * 512 * 2;  // 128KB
    unsigned short* Wgru  = (unsigned short*)(ws + off); off += (size_t)512 * 256 * 2;  // 256KB
    float*          cnt4  = (float*)(ws + off);          off += (size_t)M * 4 * 4;      // 800KB
    int* deg4     = (int*)(ws + off); off += (size_t)N4 * 4;
    int* rowptr4  = (int*)(ws + off); off += (size_t)(N4 + 1) * 4;
    int* cursor4  = (int*)(ws + off); off += (size_t)N4 * 4;
    int* blocksum = (int*)(ws + off); off += 256 * 4;
    int* blockoff = (int*)(ws + off); off += 256 * 4;
    int* csr      = (int*)(ws + off); off += (size_t)E * 4;

    const int total4 = M * HID / 4;
    const int nb_cvt = (total4 + 255) / 256;     // 6250
    const int nb_zero = (N4 + 255) / 256;        // 782
    const int nb_scan = (N4 + 1023) / 1024;      // 196 <= 256

    prep_kernel<<<nb_cvt + 769 + nb_zero, 256, 0, stream>>>(
        node_states, hbf, edge_W, Wcat, w_ih, w_hh, Wgru, bias4, b_ih, b_hh,
        deg4, total4, nb_cvt, N4);

    hist4_kernel<<<(E + 255) / 256, 256, 0, stream>>>(dst, edge_type, deg4, E);
    scan_blocks4_kernel<<<nb_scan, 256, 0, stream>>>(deg4, rowptr4, blocksum, N4);
    scan_top_kernel<<<1, 256, 0, stream>>>(blocksum, blockoff, nb_scan);
    finalize4_kernel<<<(N4 + 255) / 256, 256, 0, stream>>>(rowptr4, blockoff, cursor4, N4, E);
    fill4_kernel<<<(E + 255) / 256, 256, 0, stream>>>(src, dst, edge_type, cursor4, csr, E);

    gather_s_kernel<<<(M + 3) / 4, 256, 0, stream>>>(rowptr4, csr, (const unsigned int*)hbf,
                                                     (float4*)cnt4, (unsigned int*)S, M);

    agg_gru<<<(M + 63) / 64, 512, 0, stream>>>(S, Wcat, Wgru, hbf, (const float4*)cnt4,
                                               edge_b, (const float4*)bias4, (float*)d_out, M);
}